// Round 3
// baseline (243.597 us; speedup 1.0000x reference)
//
#include <hip/hip_runtime.h>
#include <hip/hip_bf16.h>
#include <cstdint>
#include <cstddef>

typedef __attribute__((ext_vector_type(4))) float f32x4;
typedef __attribute__((ext_vector_type(8))) short bf16x8;
typedef unsigned short ushort_t;

#define KDIM 768
#define BM 256
#define BN 256
#define BK2 32
#define NKT 24  // 768/32 K-slices

static __device__ __forceinline__ float sani(float x) {
  if (__builtin_isnan(x)) return 0.0f;
  if (__builtin_isinf(x)) return x > 0.0f ? 1.0e4f : -1.0e4f;
  return x;
}

// float -> bf16 bits, round-to-nearest-even
static __device__ __forceinline__ unsigned short f2bf(float x) {
  unsigned u = __builtin_bit_cast(unsigned, x);
  unsigned r = 0x7FFFu + ((u >> 16) & 1u);
  return (unsigned short)((u + r) >> 16);
}

// xl/wl: PLAIN row-major [row][768] bf16 (no swizzle; the GEMM realizes its
// conflict-free LDS layout via per-lane staged global addresses, m173).

__global__ __launch_bounds__(256) void prep_x_kernel(
    const float* __restrict__ h, ushort_t* __restrict__ xl,
    float* __restrict__ tx) {
  const int row = blockIdx.x;
  const int t = threadIdx.x;
  const float* src = h + (size_t)row * (KDIM + 1) + 1;  // skip given time comp
  float v0 = sani(src[t]);
  float v1 = sani(src[t + 256]);
  float v2 = sani(src[t + 512]);
  float ss = v0 * v0 + v1 * v1 + v2 * v2;
#pragma unroll
  for (int off = 32; off > 0; off >>= 1) ss += __shfl_down(ss, off);
  __shared__ float red[4];
  if ((t & 63) == 0) red[t >> 6] = ss;
  __syncthreads();
  if (t == 0) {
    float total = red[0] + red[1] + red[2] + red[3];
    tx[row] = sqrtf(1.0f + total);
  }
  ushort_t* dst = xl + (size_t)row * KDIM;
  dst[t]       = f2bf(v0);
  dst[t + 256] = f2bf(v1);
  dst[t + 512] = f2bf(v2);
}

__global__ __launch_bounds__(256) void prep_w_kernel(
    const float* __restrict__ w, ushort_t* __restrict__ wl,
    float* __restrict__ cw, int V) {
  const int row = blockIdx.x;
  const int t = threadIdx.x;
  ushort_t* dst = wl + (size_t)row * KDIM;
  if (row >= V) {  // zero-fill padded rows
    dst[t] = 0; dst[t + 256] = 0; dst[t + 512] = 0;
    if (t == 0) cw[row] = 0.0f;
    return;
  }
  const float* src = w + (size_t)row * KDIM;
  float v0 = src[t];
  float v1 = src[t + 256];
  float v2 = src[t + 512];
  float ss = v0 * v0 + v1 * v1 + v2 * v2;
#pragma unroll
  for (int off = 32; off > 0; off >>= 1) ss += __shfl_down(ss, off);
  __shared__ float red[4];
  if ((t & 63) == 0) red[t >> 6] = ss;
  __syncthreads();
  float total = red[0] + red[1] + red[2] + red[3];
  float r = sqrtf(total);
  float rc = fminf(r, 3.0f);
  float sc = sinhf(rc) / fmaxf(r, 1e-8f);
  dst[t]       = f2bf(sani(v0 * sc));
  dst[t + 256] = f2bf(sani(v1 * sc));
  dst[t + 512] = f2bf(sani(v2 * sc));
  if (t == 0) cw[row] = sani(coshf(rc));
}

#define GLD16(gp, sp)                                               \
  __builtin_amdgcn_global_load_lds(                                 \
      (const __attribute__((address_space(1))) void*)(gp),          \
      (__attribute__((address_space(3))) void*)(sp), 16, 0, 0)

// Deep-pipelined 256x256 GEMM, BK2=32 K-slices, ring-4 LDS (128 KiB),
// counted vmcnt(8) (3 slices in flight), 1 barrier per K-step.
// LDS slot layout per operand: [16 rg-blocks][4 granules][16 rows][16B]
//  -> a wave's fragment ds_read_b128 covers ONE contiguous 1KiB block
//     (lanes 0-63 at lane*16B): conflict-free, no swizzle needed.
__global__ __launch_bounds__(512, 1) void gemm_kernel(
    const ushort_t* __restrict__ xl, const ushort_t* __restrict__ wl,
    const float* __restrict__ tx, const float* __restrict__ cw,
    const float* __restrict__ ls, float* __restrict__ out,
    int V, int nwg) {
  __shared__ ushort_t ldsA[4 * 8192];  // 4 slots x 16 KiB
  __shared__ ushort_t ldsB[4 * 8192];

  const int tid = threadIdx.x;
  const int lane = tid & 63;
  const int wid = tid >> 6;   // 0..7
  const int wr = wid >> 2;    // 0..1 : wave row  (128 rows each)
  const int wc = wid & 3;     // 0..3 : wave col  (64 cols each)

  // bijective chunked XCD swizzle (m204): nwg=788, q=98, r=4
  const int g = blockIdx.x;
  const int q = nwg >> 3, rr = nwg & 7;
  const int xcd = g & 7, lid = g >> 3;
  const int L = (xcd < rr ? xcd * (q + 1) : rr * (q + 1) + (xcd - rr) * q) + lid;
  const int bm = L & 3;       // 4 M-tiles; consecutive L share bn (B-panel in XCD L2)
  const int bn = L >> 2;

  const int l15 = lane & 15;
  const int lq = lane >> 4;     // 0..3 (k-granule)
  const int g8 = lq * 8;        // staging k-offset (elements)

  const size_t a_row0 = (size_t)bm * BM;
  const size_t b_row0 = (size_t)bn * BN;

  f32x4 acc[8][4];
#pragma unroll
  for (int i = 0; i < 8; ++i)
#pragma unroll
    for (int j = 0; j < 4; ++j) acc[i][j] = (f32x4){0.f, 0.f, 0.f, 0.f};

  // Per K-slice staging: 4 gload_lds/thread (2 A + 2 B). Wave w fills
  // rg-blocks {w, w+8}. HW dest = uniform base + lane*16B -> [g][row] block.
#define STAGE(T)                                                              \
  {                                                                           \
    const int slot_ = ((T) & 3) * 8192;                                       \
    const int kb_ = (T) * BK2 + g8;                                           \
    GLD16(xl + (a_row0 + wid * 16 + l15) * KDIM + kb_,                        \
          &ldsA[slot_ + wid * 512]);                                          \
    GLD16(xl + (a_row0 + (wid + 8) * 16 + l15) * KDIM + kb_,                  \
          &ldsA[slot_ + (wid + 8) * 512]);                                    \
    GLD16(wl + (b_row0 + wid * 16 + l15) * KDIM + kb_,                        \
          &ldsB[slot_ + wid * 512]);                                          \
    GLD16(wl + (b_row0 + (wid + 8) * 16 + l15) * KDIM + kb_,                  \
          &ldsB[slot_ + (wid + 8) * 512]);                                    \
  }

#define COMPUTE(T)                                                            \
  {                                                                           \
    const ushort_t* sA_ =                                                     \
        &ldsA[((T) & 3) * 8192 + wr * 4096 + lq * 128 + l15 * 8];             \
    const ushort_t* sB_ =                                                     \
        &ldsB[((T) & 3) * 8192 + wc * 2048 + lq * 128 + l15 * 8];             \
    bf16x8 bfr[4], afr[8];                                                    \
    _Pragma("unroll") for (int ni = 0; ni < 4; ++ni)                          \
        bfr[ni] = *(const bf16x8*)&sB_[ni * 512];                             \
    _Pragma("unroll") for (int mi = 0; mi < 8; ++mi)                          \
        afr[mi] = *(const bf16x8*)&sA_[mi * 512];                             \
    _Pragma("unroll") for (int mi = 0; mi < 8; ++mi)                          \
      _Pragma("unroll") for (int ni = 0; ni < 4; ++ni)                        \
          acc[mi][ni] = __builtin_amdgcn_mfma_f32_16x16x32_bf16(              \
              bfr[ni], afr[mi], acc[mi][ni], 0, 0, 0);                        \
  }

  // prologue: 3 slices in flight
  STAGE(0);
  STAGE(1);
  STAGE(2);

  // steady state: certify slice t (all but newest 8 loads landed), barrier,
  // then overwrite slot[(t-1)&3] with slice t+3 (everyone is past reading it).
  for (int t = 0; t < NKT - 3; ++t) {
    asm volatile("s_waitcnt vmcnt(8)\n\ts_barrier" ::: "memory");
    STAGE(t + 3);
    __builtin_amdgcn_sched_barrier(0);
    COMPUTE(t);
  }
  asm volatile("s_waitcnt vmcnt(8)\n\ts_barrier" ::: "memory");
  __builtin_amdgcn_sched_barrier(0);
  COMPUTE(NKT - 3);
  asm volatile("s_waitcnt vmcnt(4)\n\ts_barrier" ::: "memory");
  __builtin_amdgcn_sched_barrier(0);
  COMPUTE(NKT - 2);
  asm volatile("s_waitcnt vmcnt(0)\n\ts_barrier" ::: "memory");
  __builtin_amdgcn_sched_barrier(0);
  COMPUTE(NKT - 1);

  float tau = ls[0];
  tau = fminf(fmaxf(tau, 0.01f), 2.5f);

  // swapped-operand C/D: m = l15 (col field), n = lq*4 + j (row field)
#pragma unroll
  for (int mi = 0; mi < 8; ++mi) {
    const int mg = bm * BM + wr * 128 + mi * 16 + l15;
    const float txm = tx[mg];
    float* orow = out + (size_t)mg * V;
#pragma unroll
    for (int ni = 0; ni < 4; ++ni) {
      const int nb = bn * BN + wc * 64 + ni * 16 + lq * 4;
      const f32x4 cw4 = *(const f32x4*)&cw[nb];
      f32x4 v;
#pragma unroll
      for (int j = 0; j < 4; ++j)
        v[j] = (acc[mi][ni][j] - txm * cw4[j]) * tau;
      if (nb + 3 < V) {
        __builtin_memcpy(&orow[nb], &v, 16);
      } else {
#pragma unroll
        for (int j = 0; j < 4; ++j)
          if (nb + j < V) orow[nb + j] = v[j];
      }
    }
  }
#undef STAGE
#undef COMPUTE
}

extern "C" void kernel_launch(void* const* d_in, const int* in_sizes, int n_in,
                              void* d_out, int out_size, void* d_ws, size_t ws_size,
                              hipStream_t stream) {
  const float* h = (const float*)d_in[0];
  const float* w = (const float*)d_in[1];
  const float* ls = (const float*)d_in[2];
  float* out = (float*)d_out;

  const int M = in_sizes[0] / (KDIM + 1);        // 1024
  const int V = in_sizes[1] / KDIM;              // 50257
  const int Vpad = (V + BN - 1) & ~(BN - 1);     // 50432

  // workspace: wl bf16 [Vpad*768] | xl bf16 [M*768] | cw f32 [Vpad] | tx f32 [M]
  char* ws = (char*)d_ws;
  ushort_t* wl = (ushort_t*)ws;
  ushort_t* xl = (ushort_t*)(ws + (size_t)Vpad * KDIM * 2);
  float* cw = (float*)(ws + (size_t)Vpad * KDIM * 2 + (size_t)M * KDIM * 2);
  float* tx = cw + Vpad;

  prep_x_kernel<<<dim3(M), dim3(256), 0, stream>>>(h, xl, tx);
  prep_w_kernel<<<dim3(Vpad), dim3(256), 0, stream>>>(w, wl, cw, V);

  const int Mtiles = M / BM;                     // 4
  const int nwg = Mtiles * (Vpad / BN);          // 788
  gemm_kernel<<<dim3(nwg), dim3(512), 0, stream>>>(
      xl, wl, tx, cw, ls, out, V, nwg);
}

// Round 4
// 223.270 us; speedup vs baseline: 1.0910x; 1.0910x over previous
//
#include <hip/hip_runtime.h>
#include <hip/hip_bf16.h>
#include <cstdint>
#include <cstddef>

typedef __attribute__((ext_vector_type(4))) float f32x4;
typedef __attribute__((ext_vector_type(8))) short bf16x8;
typedef unsigned short ushort_t;

#define KDIM 768
#define BM 128
#define BN 128
#define BK 64
#define NKT 12  // 768/64

static __device__ __forceinline__ float sani(float x) {
  if (__builtin_isnan(x)) return 0.0f;
  if (__builtin_isinf(x)) return x > 0.0f ? 1.0e4f : -1.0e4f;
  return x;
}

// float -> bf16 bits, round-to-nearest-even (prep_x only)
static __device__ __forceinline__ unsigned short f2bf(float x) {
  unsigned u = __builtin_bit_cast(unsigned, x);
  unsigned r = 0x7FFFu + ((u >> 16) & 1u);
  return (unsigned short)((u + r) >> 16);
}

// xl stored PRE-SWIZZLED: element e of row at e ^ ((row&7)<<3)  (16B-granule
// XOR; global_load_lds stages linearly, GEMM ds_read applies the same XOR).
__global__ __launch_bounds__(256) void prep_x_kernel(
    const float* __restrict__ h, ushort_t* __restrict__ xl,
    float* __restrict__ tx) {
  const int row = blockIdx.x;
  const int t = threadIdx.x;
  const int swz = (row & 7) << 3;
  const float* src = h + (size_t)row * (KDIM + 1) + 1;  // skip given time comp
  float v0 = sani(src[t]);
  float v1 = sani(src[t + 256]);
  float v2 = sani(src[t + 512]);
  float ss = v0 * v0 + v1 * v1 + v2 * v2;
#pragma unroll
  for (int off = 32; off > 0; off >>= 1) ss += __shfl_down(ss, off);
  __shared__ float red[4];
  if ((t & 63) == 0) red[t >> 6] = ss;
  __syncthreads();
  if (t == 0) {
    float total = red[0] + red[1] + red[2] + red[3];
    tx[row] = sqrtf(1.0f + total);
  }
  ushort_t* dst = xl + (size_t)row * KDIM;
  dst[t ^ swz]         = f2bf(v0);
  dst[(t + 256) ^ swz] = f2bf(v1);
  dst[(t + 512) ^ swz] = f2bf(v2);
}

#define GLD16(gp, sp)                                               \
  __builtin_amdgcn_global_load_lds(                                 \
      (const __attribute__((address_space(1))) void*)(gp),          \
      (__attribute__((address_space(3))) void*)(sp), 16, 0, 0)

// Fused GEMM: A = bf16 xl (gload_lds, swizzled storage). B = RAW fp32 weight,
// reg-staged (T14 issue-early) -> cvt_pk bf16 -> swizzled ds_write. Row norms
// accumulated in fp32 during staging; exp-map scale/cosh applied in epilogue:
//   out = (acc * sinh(rc)/max(r,eps) - t * cosh(rc)) * tau.
__global__ __launch_bounds__(256) void gemm_kernel(
    const ushort_t* __restrict__ xl, const float* __restrict__ w,
    const float* __restrict__ tx, const float* __restrict__ ls,
    float* __restrict__ out, int V, int Mtiles, int nwg8) {
  __shared__ ushort_t As[BM * BK];
  __shared__ ushort_t Bs[BN * BK];
  __shared__ float ssLds[BN];

  const int tid = threadIdx.x;
  const int lane = tid & 63;
  const int wid = tid >> 6;
  const int wr = wid >> 1;  // wave row (0..1)
  const int wc = wid & 1;   // wave col (0..1)

  // chunked XCD swizzle (nwg % 8 == 0): XCD owns contiguous L-range.
  const int g = blockIdx.x;
  const int L = (g & 7) * nwg8 + (g >> 3);
  const int bm = L & (Mtiles - 1);
  const int bn = L / Mtiles;

  const int l15 = lane & 15;
  const int lq = lane >> 4;         // 0..3 (K quarter)
  const int srow = lane >> 3;       // A staging: row within 8-row chunk
  const int scol = (lane & 7) * 8;  // A staging: k offset (8 bf16 = 16B)
  const int swz = (l15 & 7) << 3;   // ds_read element-XOR

  // B staging ids: thread covers rows {i*16+rho}, 16B chunk cch of each row
  const int rho = tid >> 4;   // 0..15
  const int cch = tid & 15;   // 0..15 (4 fp32 = 16B)

  f32x4 acc[4][4];
#pragma unroll
  for (int i = 0; i < 4; ++i)
#pragma unroll
    for (int j = 0; j < 4; ++j) acc[i][j] = (f32x4){0.f, 0.f, 0.f, 0.f};

  const int a_row0 = bm * BM;
  const int b_row0 = bn * BN;

  f32x4 breg[8];
  float ssp[8];
#pragma unroll
  for (int i = 0; i < 8; ++i) ssp[i] = 0.0f;

#define LOAD_B(T)                                                             \
  _Pragma("unroll") for (int i = 0; i < 8; ++i) {                             \
    int grow = b_row0 + i * 16 + rho;                                         \
    if (grow >= V) grow = V - 1;                                              \
    breg[i] = *(const f32x4*)&w[(size_t)grow * KDIM + (T) * BK + cch * 4];    \
  }

#define WRITE_B()                                                             \
  _Pragma("unroll") for (int i = 0; i < 8; ++i) {                             \
    const f32x4 u = breg[i];                                                  \
    ssp[i] = fmaf(u[0], u[0],                                                 \
             fmaf(u[1], u[1], fmaf(u[2], u[2], fmaf(u[3], u[3], ssp[i]))));   \
    float2 flo; flo.x = u[0]; flo.y = u[1];                                   \
    float2 fhi; fhi.x = u[2]; fhi.y = u[3];                                   \
    __hip_bfloat162 b0 = __float22bfloat162_rn(flo);                          \
    __hip_bfloat162 b1 = __float22bfloat162_rn(fhi);                          \
    uint2 pk;                                                                 \
    __builtin_memcpy(&pk.x, &b0, 4);                                          \
    __builtin_memcpy(&pk.y, &b1, 4);                                          \
    const int row = i * 16 + rho;                                             \
    *(uint2*)&Bs[row * BK + (((cch >> 1) ^ (row & 7)) << 3) +                 \
                 ((cch & 1) << 2)] = pk;                                      \
  }

#define STAGE_A(T)                                                            \
  _Pragma("unroll") for (int c = 0; c < 4; ++c) {                             \
    const int chunk = wid * 4 + c;                                            \
    const int row = chunk * 8 + srow;                                         \
    GLD16(xl + (size_t)(a_row0 + row) * KDIM + (T) * BK + scol,               \
          &As[chunk * 512]);                                                  \
  }

#define COMPUTE()                                                             \
  _Pragma("unroll") for (int kk = 0; kk < 2; ++kk) {                          \
    const int koff = (kk * 32 + lq * 8) ^ swz;                                \
    bf16x8 af[4], bfr[4];                                                     \
    _Pragma("unroll") for (int mi = 0; mi < 4; ++mi)                          \
        af[mi] = *(const bf16x8*)&As[(wr * 64 + mi * 16 + l15) * BK + koff];  \
    _Pragma("unroll") for (int ni = 0; ni < 4; ++ni)                          \
        bfr[ni] = *(const bf16x8*)&Bs[(wc * 64 + ni * 16 + l15) * BK + koff]; \
    _Pragma("unroll") for (int mi = 0; mi < 4; ++mi)                          \
      _Pragma("unroll") for (int ni = 0; ni < 4; ++ni)                        \
          acc[mi][ni] = __builtin_amdgcn_mfma_f32_16x16x32_bf16(              \
              bfr[ni], af[mi], acc[mi][ni], 0, 0, 0);                         \
  }

  LOAD_B(0);
  for (int t = 0; t < NKT; ++t) {
    __builtin_amdgcn_s_barrier();       // prev compute done -> LDS writable
    __builtin_amdgcn_sched_barrier(0);
    STAGE_A(t);                         // 4 x global_load_lds (A)
    __builtin_amdgcn_sched_barrier(0);
    WRITE_B();                          // waits own B(t) loads, cvt, ds_write
    __builtin_amdgcn_sched_barrier(0);
    if (t + 1 < NKT) {
      LOAD_B(t + 1);                    // issue-early: flies under COMPUTE(t)
      // outstanding vmem: 4 A-glds (older) + 8 B-loads (younger)
      asm volatile("s_waitcnt vmcnt(8) lgkmcnt(0)" ::: "memory");
    } else {
      asm volatile("s_waitcnt vmcnt(0) lgkmcnt(0)" ::: "memory");
    }
    __builtin_amdgcn_s_barrier();
    __builtin_amdgcn_sched_barrier(0);
    COMPUTE();
  }

  // full row sums-of-squares: reduce over the 16 chunk-threads (same wave)
#pragma unroll
  for (int i = 0; i < 8; ++i) {
    float s = ssp[i];
    s += __shfl_xor(s, 1);
    s += __shfl_xor(s, 2);
    s += __shfl_xor(s, 4);
    s += __shfl_xor(s, 8);
    ssp[i] = s;
  }
  if (cch == 0) {
#pragma unroll
    for (int i = 0; i < 8; ++i) ssLds[i * 16 + rho] = ssp[i];
  }
  __syncthreads();

  float tau = ls[0];
  tau = fminf(fmaxf(tau, 0.01f), 2.5f);

  // per-ni exp-map scalars for rows nb..nb+3 (local rows wc*64+ni*16+lq*4)
  f32x4 ch4[4], sc4[4];
#pragma unroll
  for (int ni = 0; ni < 4; ++ni) {
    const f32x4 ss4 = *(const f32x4*)&ssLds[wc * 64 + ni * 16 + lq * 4];
#pragma unroll
    for (int j = 0; j < 4; ++j) {
      const float r = sqrtf(ss4[j]);
      const float rc = fminf(r, 3.0f);
      const float e = expf(rc);
      const float ei = 1.0f / e;
      ch4[ni][j] = 0.5f * (e + ei);
      sc4[ni][j] = (0.5f * (e - ei)) / fmaxf(r, 1e-8f);
    }
  }

#pragma unroll
  for (int mi = 0; mi < 4; ++mi) {
    const int mg = a_row0 + wr * 64 + mi * 16 + l15;
    const float txm = tx[mg];
    float* orow = out + (size_t)mg * V;
#pragma unroll
    for (int ni = 0; ni < 4; ++ni) {
      const int nb = b_row0 + wc * 64 + ni * 16 + lq * 4;
      f32x4 v;
#pragma unroll
      for (int j = 0; j < 4; ++j)
        v[j] = (acc[mi][ni][j] * sc4[ni][j] - txm * ch4[ni][j]) * tau;
      if (nb + 3 < V) {
        __builtin_memcpy(&orow[nb], &v, 16);
      } else {
#pragma unroll
        for (int j = 0; j < 4; ++j)
          if (nb + j < V) orow[nb + j] = v[j];
      }
    }
  }
#undef LOAD_B
#undef WRITE_B
#undef STAGE_A
#undef COMPUTE
}

extern "C" void kernel_launch(void* const* d_in, const int* in_sizes, int n_in,
                              void* d_out, int out_size, void* d_ws, size_t ws_size,
                              hipStream_t stream) {
  const float* h = (const float*)d_in[0];
  const float* w = (const float*)d_in[1];
  const float* ls = (const float*)d_in[2];
  float* out = (float*)d_out;

  const int M = in_sizes[0] / (KDIM + 1);        // 1024
  const int V = in_sizes[1] / KDIM;              // 50257
  const int Vpad = (V + BN - 1) & ~(BN - 1);     // 50304

  // workspace: xl bf16 [M*768] | tx f32 [M]
  char* ws = (char*)d_ws;
  ushort_t* xl = (ushort_t*)ws;
  float* tx = (float*)(ws + (size_t)M * KDIM * 2);

  prep_x_kernel<<<dim3(M), dim3(256), 0, stream>>>(h, xl, tx);

  const int Mtiles = M / BM;                     // 8
  const int nwg = Mtiles * (Vpad / BN);          // 3144 (divisible by 8)
  gemm_kernel<<<dim3(nwg), dim3(256), 0, stream>>>(
      xl, w, tx, ls, out, V, Mtiles, nwg / 8);
}

// Round 5
// 212.544 us; speedup vs baseline: 1.1461x; 1.0505x over previous
//
#include <hip/hip_runtime.h>
#include <hip/hip_bf16.h>
#include <cstdint>
#include <cstddef>

typedef __attribute__((ext_vector_type(4))) float f32x4;
typedef __attribute__((ext_vector_type(8))) short bf16x8;
typedef unsigned short ushort_t;

#define KDIM 768
#define BM 128
#define BN 128
#define BK 64
#define NKT 12  // 768/64

static __device__ __forceinline__ float sani(float x) {
  if (__builtin_isnan(x)) return 0.0f;
  if (__builtin_isinf(x)) return x > 0.0f ? 1.0e4f : -1.0e4f;
  return x;
}

// float -> bf16 bits, round-to-nearest-even
static __device__ __forceinline__ unsigned short f2bf(float x) {
  unsigned u = __builtin_bit_cast(unsigned, x);
  unsigned r = 0x7FFFu + ((u >> 16) & 1u);
  return (unsigned short)((u + r) >> 16);
}

// xl/wl stored PRE-SWIZZLED: element e of row at e ^ ((row&7)<<3) (16B-granule
// XOR). global_load_lds stages linearly; the GEMM ds_read applies the same
// XOR (both-sides rule) -> conflict-free ds_read_b128 (verified: 0 conflicts).

__global__ __launch_bounds__(256) void prep_x_kernel(
    const float* __restrict__ h, ushort_t* __restrict__ xl,
    float* __restrict__ tx) {
  const int row = blockIdx.x;
  const int t = threadIdx.x;
  const int swz = (row & 7) << 3;
  const float* src = h + (size_t)row * (KDIM + 1) + 1;  // skip given time comp
  float v0 = sani(src[t]);
  float v1 = sani(src[t + 256]);
  float v2 = sani(src[t + 512]);
  float ss = v0 * v0 + v1 * v1 + v2 * v2;
#pragma unroll
  for (int off = 32; off > 0; off >>= 1) ss += __shfl_down(ss, off);
  __shared__ float red[4];
  if ((t & 63) == 0) red[t >> 6] = ss;
  __syncthreads();
  if (t == 0) {
    float total = red[0] + red[1] + red[2] + red[3];
    tx[row] = sqrtf(1.0f + total);
  }
  ushort_t* dst = xl + (size_t)row * KDIM;
  dst[t ^ swz]         = f2bf(v0);
  dst[(t + 256) ^ swz] = f2bf(v1);
  dst[(t + 512) ^ swz] = f2bf(v2);
}

__global__ __launch_bounds__(256) void prep_w_kernel(
    const float* __restrict__ w, ushort_t* __restrict__ wl,
    float* __restrict__ cw, int V) {
  const int row = blockIdx.x;
  const int t = threadIdx.x;
  const int swz = (row & 7) << 3;
  ushort_t* dst = wl + (size_t)row * KDIM;
  if (row >= V) {  // zero-fill padded rows
    dst[t] = 0; dst[t + 256] = 0; dst[t + 512] = 0;
    if (t == 0) cw[row] = 0.0f;
    return;
  }
  const float* src = w + (size_t)row * KDIM;
  float v0 = src[t];
  float v1 = src[t + 256];
  float v2 = src[t + 512];
  float ss = v0 * v0 + v1 * v1 + v2 * v2;
#pragma unroll
  for (int off = 32; off > 0; off >>= 1) ss += __shfl_down(ss, off);
  __shared__ float red[4];
  if ((t & 63) == 0) red[t >> 6] = ss;
  __syncthreads();
  float total = red[0] + red[1] + red[2] + red[3];
  float r = sqrtf(total);
  float rc = fminf(r, 3.0f);
  float sc = sinhf(rc) / fmaxf(r, 1e-8f);
  dst[t ^ swz]         = f2bf(sani(v0 * sc));
  dst[(t + 256) ^ swz] = f2bf(sani(v1 * sc));
  dst[(t + 512) ^ swz] = f2bf(sani(v2 * sc));
  if (t == 0) cw[row] = sani(coshf(rc));
}

#define GLD16(gp, sp)                                               \
  __builtin_amdgcn_global_load_lds(                                 \
      (const __attribute__((address_space(1))) void*)(gp),          \
      (__attribute__((address_space(3))) void*)(sp), 16, 0, 0)

// 128x128 MFMA GEMM, BK=64, DOUBLE-BUFFERED (T3 minimum 2-phase):
// STAGE(t+1) issues before COMPUTE(t); one counted vmcnt(0) + raw s_barrier
// per K-step AFTER compute (prefetch lands under the MFMAs; no __syncthreads
// early-drain). Epilogue: out = (acc - tx*cw) * tau.
__global__ __launch_bounds__(256) void gemm_kernel(
    const ushort_t* __restrict__ xl, const ushort_t* __restrict__ wl,
    const float* __restrict__ tx, const float* __restrict__ cw,
    const float* __restrict__ ls, float* __restrict__ out,
    int V, int Mtiles, int nwg8) {
  __shared__ ushort_t As[2][BM * BK];  // 2 x 16 KiB
  __shared__ ushort_t Bs[2][BN * BK];  // 2 x 16 KiB

  const int tid = threadIdx.x;
  const int lane = tid & 63;
  const int wid = tid >> 6;
  const int wr = wid >> 1;  // wave row (0..1)
  const int wc = wid & 1;   // wave col (0..1)

  // chunked XCD swizzle: XCD (= g%8) owns a contiguous L-range -> the 8
  // bm-blocks of one bn land on the same XCD's L2 (B-panel fetched once/XCD).
  const int g = blockIdx.x;
  const int L = (g & 7) * nwg8 + (g >> 3);
  const int bm = L & (Mtiles - 1);
  const int bn = L / Mtiles;

  const int l15 = lane & 15;
  const int lq = lane >> 4;         // 0..3 (K quarter)
  const int srow = lane >> 3;       // staging: row within 8-row chunk
  const int scol = (lane & 7) * 8;  // staging: k offset (8 bf16 = 16B)
  const int swz = (l15 & 7) << 3;   // ds_read element-XOR (matches storage)

  f32x4 acc[4][4];
#pragma unroll
  for (int i = 0; i < 4; ++i)
#pragma unroll
    for (int j = 0; j < 4; ++j) acc[i][j] = (f32x4){0.f, 0.f, 0.f, 0.f};

  const size_t a_row0 = (size_t)bm * BM;
  const size_t b_row0 = (size_t)bn * BN;

#define STAGE(B_, T_)                                                         \
  _Pragma("unroll") for (int c = 0; c < 4; ++c) {                             \
    const int chunk = wid * 4 + c;                                            \
    const int row = chunk * 8 + srow;                                         \
    GLD16(xl + (a_row0 + row) * KDIM + (T_) * BK + scol,                      \
          &As[B_][chunk * 512]);                                              \
    GLD16(wl + (b_row0 + row) * KDIM + (T_) * BK + scol,                      \
          &Bs[B_][chunk * 512]);                                              \
  }

#define COMPUTE(B_)                                                           \
  _Pragma("unroll") for (int kk = 0; kk < 2; ++kk) {                          \
    const int koff = (kk * 32 + lq * 8) ^ swz;                                \
    bf16x8 af[4], bfr[4];                                                     \
    _Pragma("unroll") for (int mi = 0; mi < 4; ++mi)                          \
        af[mi] =                                                              \
            *(const bf16x8*)&As[B_][(wr * 64 + mi * 16 + l15) * BK + koff];   \
    _Pragma("unroll") for (int ni = 0; ni < 4; ++ni)                          \
        bfr[ni] =                                                             \
            *(const bf16x8*)&Bs[B_][(wc * 64 + ni * 16 + l15) * BK + koff];   \
    _Pragma("unroll") for (int mi = 0; mi < 4; ++mi)                          \
      _Pragma("unroll") for (int ni = 0; ni < 4; ++ni)                        \
          acc[mi][ni] = __builtin_amdgcn_mfma_f32_16x16x32_bf16(              \
              bfr[ni], af[mi], acc[mi][ni], 0, 0, 0);                         \
  }

  // prologue: fill buffer 0
  STAGE(0, 0);
  asm volatile("s_waitcnt vmcnt(0)" ::: "memory");
  __builtin_amdgcn_s_barrier();

#pragma unroll 2
  for (int t = 0; t < NKT; ++t) {
    const int cur = t & 1;
    if (t + 1 < NKT) STAGE(cur ^ 1, t + 1);  // prefetch flies under compute
    __builtin_amdgcn_sched_barrier(0);
    COMPUTE(cur);
    __builtin_amdgcn_sched_barrier(0);
    asm volatile("s_waitcnt vmcnt(0)" ::: "memory");  // prefetch landed
    __builtin_amdgcn_s_barrier();                     // all reads of cur done
  }

  float tau = ls[0];
  tau = fminf(fmaxf(tau, 0.01f), 2.5f);

  // swapped-operand C/D: m = l15 (col field), n = lq*4 + j (row field)
#pragma unroll
  for (int mi = 0; mi < 4; ++mi) {
    const int mg = (int)a_row0 + wr * 64 + mi * 16 + l15;
    const float txm = tx[mg];
    float* orow = out + (size_t)mg * V;
#pragma unroll
    for (int ni = 0; ni < 4; ++ni) {
      const int nb = (int)b_row0 + wc * 64 + ni * 16 + lq * 4;
      const f32x4 cw4 = *(const f32x4*)&cw[nb];  // nb%4==0 -> 16B aligned
      f32x4 v;
#pragma unroll
      for (int j = 0; j < 4; ++j)
        v[j] = (acc[mi][ni][j] - txm * cw4[j]) * tau;
      if (nb + 3 < V) {
        __builtin_memcpy(&orow[nb], &v, 16);  // 4B-aligned 16B store
      } else {
#pragma unroll
        for (int j = 0; j < 4; ++j)
          if (nb + j < V) orow[nb + j] = v[j];
      }
    }
  }
#undef STAGE
#undef COMPUTE
}

extern "C" void kernel_launch(void* const* d_in, const int* in_sizes, int n_in,
                              void* d_out, int out_size, void* d_ws, size_t ws_size,
                              hipStream_t stream) {
  const float* h = (const float*)d_in[0];
  const float* w = (const float*)d_in[1];
  const float* ls = (const float*)d_in[2];
  float* out = (float*)d_out;

  const int M = in_sizes[0] / (KDIM + 1);        // 1024
  const int V = in_sizes[1] / KDIM;              // 50257
  const int Vpad = (V + BN - 1) & ~(BN - 1);     // 50304

  // workspace: wl bf16 [Vpad*768] | xl bf16 [M*768] | cw f32 [Vpad] | tx f32 [M]
  char* ws = (char*)d_ws;
  ushort_t* wl = (ushort_t*)ws;
  ushort_t* xl = (ushort_t*)(ws + (size_t)Vpad * KDIM * 2);
  float* cw = (float*)(ws + (size_t)Vpad * KDIM * 2 + (size_t)M * KDIM * 2);
  float* tx = cw + Vpad;

  prep_x_kernel<<<dim3(M), dim3(256), 0, stream>>>(h, xl, tx);
  prep_w_kernel<<<dim3(Vpad), dim3(256), 0, stream>>>(w, wl, cw, V);

  const int Mtiles = M / BM;                     // 8
  const int nwg = Mtiles * (Vpad / BN);          // 3144 (divisible by 8)
  gemm_kernel<<<dim3(nwg), dim3(256), 0, stream>>>(
      xl, wl, tx, cw, ls, out, V, Mtiles, nwg / 8);
}

// Round 6
// 191.402 us; speedup vs baseline: 1.2727x; 1.1105x over previous
//
#include <hip/hip_runtime.h>
#include <hip/hip_bf16.h>
#include <cstdint>
#include <cstddef>

typedef __attribute__((ext_vector_type(4))) float f32x4;
typedef __attribute__((ext_vector_type(8))) short bf16x8;
typedef unsigned short ushort_t;

#define KDIM 768
#define BM 256
#define BN 256
#define BK 64
#define NKT 12  // 768/64

static __device__ __forceinline__ float sani(float x) {
  if (__builtin_isnan(x)) return 0.0f;
  if (__builtin_isinf(x)) return x > 0.0f ? 1.0e4f : -1.0e4f;
  return x;
}

static __device__ __forceinline__ unsigned short f2bf(float x) {
  unsigned u = __builtin_bit_cast(unsigned, x);
  unsigned r = 0x7FFFu + ((u >> 16) & 1u);
  return (unsigned short)((u + r) >> 16);
}

// xl/wl: PLAIN row-major bf16 [row][768]. The GEMM realizes swizzled LDS
// layouts via per-lane pre-swizzled GLOBAL source addresses (m173 pattern).

__global__ __launch_bounds__(256) void prep_x_kernel(
    const float* __restrict__ h, ushort_t* __restrict__ xl,
    float* __restrict__ tx) {
  const int row = blockIdx.x;
  const int t = threadIdx.x;
  const float* src = h + (size_t)row * (KDIM + 1) + 1;
  float v0 = sani(src[t]);
  float v1 = sani(src[t + 256]);
  float v2 = sani(src[t + 512]);
  float ss = v0 * v0 + v1 * v1 + v2 * v2;
#pragma unroll
  for (int off = 32; off > 0; off >>= 1) ss += __shfl_down(ss, off);
  __shared__ float red[4];
  if ((t & 63) == 0) red[t >> 6] = ss;
  __syncthreads();
  if (t == 0) {
    float total = red[0] + red[1] + red[2] + red[3];
    tx[row] = sqrtf(1.0f + total);
  }
  ushort_t* dst = xl + (size_t)row * KDIM;
  dst[t]       = f2bf(v0);
  dst[t + 256] = f2bf(v1);
  dst[t + 512] = f2bf(v2);
}

__global__ __launch_bounds__(256) void prep_w_kernel(
    const float* __restrict__ w, ushort_t* __restrict__ wl,
    float* __restrict__ cw, int V) {
  const int row = blockIdx.x;
  const int t = threadIdx.x;
  ushort_t* dst = wl + (size_t)row * KDIM;
  if (row >= V) {
    dst[t] = 0; dst[t + 256] = 0; dst[t + 512] = 0;
    if (t == 0) cw[row] = 0.0f;
    return;
  }
  const float* src = w + (size_t)row * KDIM;
  float v0 = src[t];
  float v1 = src[t + 256];
  float v2 = src[t + 512];
  float ss = v0 * v0 + v1 * v1 + v2 * v2;
#pragma unroll
  for (int off = 32; off > 0; off >>= 1) ss += __shfl_down(ss, off);
  __shared__ float red[4];
  if ((t & 63) == 0) red[t >> 6] = ss;
  __syncthreads();
  float total = red[0] + red[1] + red[2] + red[3];
  float r = sqrtf(total);
  float rc = fminf(r, 3.0f);
  float sc = sinhf(rc) / fmaxf(r, 1e-8f);
  dst[t]       = f2bf(sani(v0 * sc));
  dst[t + 256] = f2bf(sani(v1 * sc));
  dst[t + 512] = f2bf(sani(v2 * sc));
  if (t == 0) cw[row] = sani(coshf(rc));
}

#define GLD16(gp, sp)                                               \
  __builtin_amdgcn_global_load_lds(                                 \
      (const __attribute__((address_space(1))) void*)(gp),          \
      (__attribute__((address_space(3))) void*)(sp), 16, 0, 0)

// 256x256 8-wave GEMM, BK=64, ring-2 LDS (128 KiB), 4 fine phases per K-tile
// with counted vmcnt (never 0 in steady state). Per buffer (32768 ushort):
//   A: [kk-half][256 rows][32 elems], granule swizzle g ^= (row&3)
//   B: [wc-quarter][64 rows][64 elems], granule swizzle g ^= (row&7)
// Stage order per tile t+1 during tile t: BQ01@ph0, BQ23@ph1, AK0@ph2, AK1@ph3
// Certify: vmcnt(4)@ph1 (AK1(t) for ph2), vmcnt(2)@ph3 (BQ*,AK0(t+1) for ph0).
__global__ __launch_bounds__(512, 2) void gemm_kernel(
    const ushort_t* __restrict__ xl, const ushort_t* __restrict__ wl,
    const float* __restrict__ tx, const float* __restrict__ cw,
    const float* __restrict__ ls, float* __restrict__ out,
    int V, int nwg) {
  __shared__ ushort_t lds[65536];  // 2 x 32768 (128 KiB)

  const int tid = threadIdx.x;
  const int lane = tid & 63;
  const int wid = tid >> 6;   // 0..7
  const int wr = wid >> 2;    // 0..1  (128 A-rows each)
  const int wc = wid & 3;     // 0..3  (64 B-rows each)

  // bijective chunked XCD swizzle (m204)
  const int g = blockIdx.x;
  const int q = nwg >> 3, rr = nwg & 7;
  const int xcd = g & 7, lid = g >> 3;
  const int L = (xcd < rr ? xcd * (q + 1) : rr * (q + 1) + (xcd - rr) * q) + lid;
  const int bm = L & 3;   // 4 M-tiles; consecutive L share bn
  const int bn = L >> 2;

  const int l15 = lane & 15;
  const int lq = lane >> 4;  // 0..3

  const int a_row0 = bm * BM;
  const int b_row0 = bn * BN;

  // ---- staging source bases (per-lane pre-swizzled global addresses) ----
  const int w8l = wid * 8 + (lane >> 3);                    // B row-local
  const int bswz = (((lane & 7) ^ (lane >> 3)) & 7) << 3;   // B granule swz
  size_t bsrc[4];
#pragma unroll
  for (int qq = 0; qq < 4; ++qq)
    bsrc[qq] = (size_t)(b_row0 + qq * 64 + w8l) * KDIM + bswz;

  const int arl = wid * 16 + (lane >> 2);                   // A row-local (+r*128)
  const int aswz = (((lane & 3) ^ ((lane >> 2) & 3)) & 3) << 3;
  size_t asrc[2];
#pragma unroll
  for (int rsub = 0; rsub < 2; ++rsub)
    asrc[rsub] = (size_t)(a_row0 + arl + rsub * 128) * KDIM + aswz;

  // ---- ds_read offsets (elements) ----
  const int aoff = (wr * 128 + l15) * 32 + ((lq ^ (l15 & 3)) << 3);
  const int boff = wc * 4096 + l15 * 64;
  const int bg0 = ((lq) ^ (l15 & 7)) << 3;        // kk=0 granule
  const int bg1 = ((4 + lq) ^ (l15 & 7)) << 3;    // kk=1 granule

  f32x4 acc[8][4];
#pragma unroll
  for (int i = 0; i < 8; ++i)
#pragma unroll
    for (int j = 0; j < 4; ++j) acc[i][j] = (f32x4){0.f, 0.f, 0.f, 0.f};

  bf16x8 af[8], bq[2];

#define STAGE_BQ(NXT, Q, T)                                                   \
  GLD16(wl + bsrc[Q] + (size_t)(T) * BK,                                      \
        &lds[(NXT) + 16384 + (Q) * 4096 + wid * 512])

#define STAGE_AK(NXT, HK, T)                                                  \
  {                                                                           \
    GLD16(xl + asrc[0] + (size_t)(T) * BK + (HK) * 32,                        \
          &lds[(NXT) + (HK) * 8192 + wid * 512]);                             \
    GLD16(xl + asrc[1] + (size_t)(T) * BK + (HK) * 32,                        \
          &lds[(NXT) + (HK) * 8192 + wid * 512 + 4096]);                      \
  }

#define READ_A(CUR, KK)                                                       \
  _Pragma("unroll") for (int mi = 0; mi < 8; ++mi)                            \
      af[mi] = *(const bf16x8*)&lds[(CUR) + (KK) * 8192 + aoff + mi * 512];

#define READ_B(CUR, KK, NIH)                                                  \
  _Pragma("unroll") for (int j = 0; j < 2; ++j)                               \
      bq[j] = *(const bf16x8*)&lds[(CUR) + 16384 + boff +                     \
                                   ((NIH) * 2 + j) * 1024 +                   \
                                   ((KK) ? bg1 : bg0)];

#define MFMA16(NIH)                                                           \
  __builtin_amdgcn_s_setprio(1);                                              \
  _Pragma("unroll") for (int mi = 0; mi < 8; ++mi)                            \
    _Pragma("unroll") for (int j = 0; j < 2; ++j)                             \
        acc[mi][(NIH) * 2 + j] = __builtin_amdgcn_mfma_f32_16x16x32_bf16(     \
            bq[j], af[mi], acc[mi][(NIH) * 2 + j], 0, 0, 0);                  \
  __builtin_amdgcn_s_setprio(0);

#define BAR __builtin_amdgcn_s_barrier()
#define LGKM0                                                                 \
  do {                                                                        \
    asm volatile("s_waitcnt lgkmcnt(0)" ::: "memory");                        \
    __builtin_amdgcn_sched_barrier(0);                                        \
  } while (0)

  // prologue: stage tile 0 into buf0 in consumption order
  STAGE_BQ(0, 0, 0); STAGE_BQ(0, 1, 0); STAGE_BQ(0, 2, 0); STAGE_BQ(0, 3, 0);
  STAGE_AK(0, 0, 0);
  STAGE_AK(0, 1, 0);
  asm volatile("s_waitcnt vmcnt(2)" ::: "memory");  // AK1(0) may still fly
  BAR;

  for (int t = 0; t < NKT - 1; ++t) {
    const int cur = (t & 1) << 15;
    const int nxt = cur ^ 32768;
    const int tn = t + 1;
    // ph0: kk0, ni01
    READ_A(cur, 0);
    READ_B(cur, 0, 0);
    STAGE_BQ(nxt, 0, tn); STAGE_BQ(nxt, 1, tn);
    BAR; LGKM0;
    MFMA16(0);
    BAR;
    // ph1: kk0, ni23
    READ_B(cur, 0, 1);
    STAGE_BQ(nxt, 2, tn); STAGE_BQ(nxt, 3, tn);
    BAR; LGKM0;
    MFMA16(1);
    asm volatile("s_waitcnt vmcnt(4)" ::: "memory");  // certify AK1(t)
    BAR;
    // ph2: kk1, ni01
    READ_A(cur, 1);
    READ_B(cur, 1, 0);
    STAGE_AK(nxt, 0, tn);
    BAR; LGKM0;
    MFMA16(0);
    BAR;
    // ph3: kk1, ni23
    READ_B(cur, 1, 1);
    STAGE_AK(nxt, 1, tn);
    BAR; LGKM0;
    MFMA16(1);
    asm volatile("s_waitcnt vmcnt(2)" ::: "memory");  // certify BQ*,AK0(t+1)
    BAR;
  }
  {  // peeled last tile (no staging; drain AK1 before kk1)
    const int cur = ((NKT - 1) & 1) << 15;
    READ_A(cur, 0);
    READ_B(cur, 0, 0);
    BAR; LGKM0;
    MFMA16(0);
    BAR;
    READ_B(cur, 0, 1);
    BAR; LGKM0;
    MFMA16(1);
    asm volatile("s_waitcnt vmcnt(0)" ::: "memory");
    BAR;
    READ_A(cur, 1);
    READ_B(cur, 1, 0);
    BAR; LGKM0;
    MFMA16(0);
    BAR;
    READ_B(cur, 1, 1);
    BAR; LGKM0;
    MFMA16(1);
  }

  float tau = ls[0];
  tau = fminf(fmaxf(tau, 0.01f), 2.5f);

  // swapped-operand C/D: m = l15 (col field), n = lq*4 + j (row field)
#pragma unroll
  for (int mi = 0; mi < 8; ++mi) {
    const int mg = a_row0 + wr * 128 + mi * 16 + l15;
    const float txm = tx[mg];
    float* orow = out + (size_t)mg * V;
#pragma unroll
    for (int ni = 0; ni < 4; ++ni) {
      const int nb = b_row0 + wc * 64 + ni * 16 + lq * 4;
      const f32x4 cw4 = *(const f32x4*)&cw[nb];
      f32x4 v;
#pragma unroll
      for (int j = 0; j < 4; ++j)
        v[j] = (acc[mi][ni][j] - txm * cw4[j]) * tau;
      if (nb + 3 < V) {
        __builtin_memcpy(&orow[nb], &v, 16);
      } else {
#pragma unroll
        for (int j = 0; j < 4; ++j)
          if (nb + j < V) orow[nb + j] = v[j];
      }
    }
  }
#undef STAGE_BQ
#undef STAGE_AK
#undef READ_A
#undef READ_B
#undef MFMA16
#undef BAR
#undef LGKM0
}

extern "C" void kernel_launch(void* const* d_in, const int* in_sizes, int n_in,
                              void* d_out, int out_size, void* d_ws, size_t ws_size,
                              hipStream_t stream) {
  const float* h = (const float*)d_in[0];
  const float* w = (const float*)d_in[1];
  const float* ls = (const float*)d_in[2];
  float* out = (float*)d_out;

  const int M = in_sizes[0] / (KDIM + 1);        // 1024
  const int V = in_sizes[1] / KDIM;              // 50257
  const int Vpad = (V + BN - 1) & ~(BN - 1);     // 50432

  // workspace: wl bf16 [Vpad*768] | xl bf16 [M*768] | cw f32 [Vpad] | tx f32 [M]
  char* ws = (char*)d_ws;
  ushort_t* wl = (ushort_t*)ws;
  ushort_t* xl = (ushort_t*)(ws + (size_t)Vpad * KDIM * 2);
  float* cw = (float*)(ws + (size_t)Vpad * KDIM * 2 + (size_t)M * KDIM * 2);
  float* tx = cw + Vpad;

  prep_x_kernel<<<dim3(M), dim3(256), 0, stream>>>(h, xl, tx);
  prep_w_kernel<<<dim3(Vpad), dim3(256), 0, stream>>>(w, wl, cw, V);

  const int Mtiles = M / BM;                     // 4
  const int nwg = Mtiles * (Vpad / BN);          // 788
  gemm_kernel<<<dim3(nwg), dim3(512), 0, stream>>>(
      xl, wl, tx, cw, ls, out, V, nwg);
}

// Round 7
// 190.355 us; speedup vs baseline: 1.2797x; 1.0055x over previous
//
#include <hip/hip_runtime.h>
#include <hip/hip_bf16.h>
#include <cstdint>
#include <cstddef>

typedef __attribute__((ext_vector_type(4))) float f32x4;
typedef __attribute__((ext_vector_type(8))) short bf16x8;
typedef unsigned short ushort_t;

#define KDIM 768
#define BM 128
#define BN 128
#define BK 32
#define NKT 24  // 768/32

static __device__ __forceinline__ float sani(float x) {
  if (__builtin_isnan(x)) return 0.0f;
  if (__builtin_isinf(x)) return x > 0.0f ? 1.0e4f : -1.0e4f;
  return x;
}

static __device__ __forceinline__ unsigned short f2bf(float x) {
  unsigned u = __builtin_bit_cast(unsigned, x);
  unsigned r = 0x7FFFu + ((u >> 16) & 1u);
  return (unsigned short)((u + r) >> 16);
}

// xl/wl: PLAIN row-major bf16 [row][768]; GEMM realizes its swizzled LDS
// layout via per-lane pre-swizzled GLOBAL source addresses (m173).

__global__ __launch_bounds__(256) void prep_x_kernel(
    const float* __restrict__ h, ushort_t* __restrict__ xl,
    float* __restrict__ tx) {
  const int row = blockIdx.x;
  const int t = threadIdx.x;
  const float* src = h + (size_t)row * (KDIM + 1) + 1;  // skip time comp
  float v0 = sani(src[t]);
  float v1 = sani(src[t + 256]);
  float v2 = sani(src[t + 512]);
  float ss = v0 * v0 + v1 * v1 + v2 * v2;
#pragma unroll
  for (int off = 32; off > 0; off >>= 1) ss += __shfl_down(ss, off);
  __shared__ float red[4];
  if ((t & 63) == 0) red[t >> 6] = ss;
  __syncthreads();
  if (t == 0) {
    float total = red[0] + red[1] + red[2] + red[3];
    tx[row] = sqrtf(1.0f + total);
  }
  ushort_t* dst = xl + (size_t)row * KDIM;
  dst[t]       = f2bf(v0);
  dst[t + 256] = f2bf(v1);
  dst[t + 512] = f2bf(v2);
}

__global__ __launch_bounds__(256) void prep_w_kernel(
    const float* __restrict__ w, ushort_t* __restrict__ wl,
    float* __restrict__ cw, int V) {
  const int row = blockIdx.x;
  const int t = threadIdx.x;
  ushort_t* dst = wl + (size_t)row * KDIM;
  if (row >= V) {
    dst[t] = 0; dst[t + 256] = 0; dst[t + 512] = 0;
    if (t == 0) cw[row] = 0.0f;
    return;
  }
  const float* src = w + (size_t)row * KDIM;
  float v0 = src[t];
  float v1 = src[t + 256];
  float v2 = src[t + 512];
  float ss = v0 * v0 + v1 * v1 + v2 * v2;
#pragma unroll
  for (int off = 32; off > 0; off >>= 1) ss += __shfl_down(ss, off);
  __shared__ float red[4];
  if ((t & 63) == 0) red[t >> 6] = ss;
  __syncthreads();
  float total = red[0] + red[1] + red[2] + red[3];
  float r = sqrtf(total);
  float rc = fminf(r, 3.0f);
  float sc = sinhf(rc) / fmaxf(r, 1e-8f);
  dst[t]       = f2bf(sani(v0 * sc));
  dst[t + 256] = f2bf(sani(v1 * sc));
  dst[t + 512] = f2bf(sani(v2 * sc));
  if (t == 0) cw[row] = sani(coshf(rc));
}

#define GLD16(gp, sp)                                               \
  __builtin_amdgcn_global_load_lds(                                 \
      (const __attribute__((address_space(1))) void*)(gp),          \
      (__attribute__((address_space(3))) void*)(sp), 16, 0, 0)

// 128x128 GEMM, BK=32, ring-3 LDS (48 KiB -> 2 blocks/CU), 4 waves.
// LDS layout per slot: A[64 ldsrows][64 el] + B[64][64]; logical row R,
// granule g (8 bf16) stored at ldsrow=R>>1, gphys=((R&1)*4+g)^(ldsrow&7):
// full 3-bit swizzle -> ds_read_b128 hits each bank-quad uniformly 8x.
// Ring-3 pipeline: STAGE(t+2) -> vmcnt(8) certifies stage(t) -> BAR ->
// READ(t) -> lgkm0 -> BAR -> MFMA(t). vmcnt never drains below 8 in steady
// state; 2 barriers/iter; cross-block TLP (2/CU) hides the rest.
__global__ __launch_bounds__(256, 2) void gemm_kernel(
    const ushort_t* __restrict__ xl, const ushort_t* __restrict__ wl,
    const float* __restrict__ tx, const float* __restrict__ cw,
    const float* __restrict__ ls, float* __restrict__ out,
    int V, int Mtiles, int nwg8) {
  __shared__ ushort_t lds[3 * 8192];  // 3 slots x (A 8KB + B 8KB)

  const int tid = threadIdx.x;
  const int lane = tid & 63;
  const int wid = tid >> 6;  // 0..3
  const int wr = wid >> 1;   // 0..1
  const int wc = wid & 1;    // 0..1

  // chunked XCD swizzle (nwg divisible by 8)
  const int g = blockIdx.x;
  const int L = (g & 7) * nwg8 + (g >> 3);
  const int bm = L & (Mtiles - 1);
  const int bn = L / Mtiles;

  const int l15 = lane & 15;
  const int lq = lane >> 4;  // 0..3

  const int a_row0 = bm * BM;
  const int b_row0 = bn * BN;

  // ---- staging source mapping (inverse of LDS layout) ----
  // lane l of a 1KB wave-chunk writes ldsrow_local=l>>3, gphys=l&7;
  // gg = gphys ^ (ldsrow&7); logical row_local = 2*(l>>3)+(gg>>2); col=(gg&3)*8
  const int ggl = (lane & 7) ^ (lane >> 3);
  const int rl = 2 * (lane >> 3) + (ggl >> 2);
  const int cg = (ggl & 3) * 8;
  // A chunks wid, wid+4 cover rows 16*wid..+15 and 16*(wid+4)..+15
  const size_t axs0 = (size_t)(a_row0 + 16 * wid + rl) * KDIM + cg;
  const size_t axs1 = (size_t)(a_row0 + 16 * (wid + 4) + rl) * KDIM + cg;
  const size_t bxs0 = (size_t)(b_row0 + 16 * wid + rl) * KDIM + cg;
  const size_t bxs1 = (size_t)(b_row0 + 16 * (wid + 4) + rl) * KDIM + cg;

  // ---- ds_read offsets (ushort elements) ----
  const int rphys = l15 >> 1;
  const int gph = (((l15 & 1) << 2) + lq) ^ rphys;  // 0..7
  const int aoff = wr * 2048 + rphys * 64 + gph * 8;
  const int boff = 4096 + wc * 2048 + rphys * 64 + gph * 8;

  f32x4 acc[4][4];
#pragma unroll
  for (int i = 0; i < 4; ++i)
#pragma unroll
    for (int j = 0; j < 4; ++j) acc[i][j] = (f32x4){0.f, 0.f, 0.f, 0.f};

#define STAGE(T_, S_)                                                         \
  {                                                                           \
    GLD16(xl + axs0 + (T_) * BK, &lds[(S_) * 8192 + wid * 512]);              \
    GLD16(xl + axs1 + (T_) * BK, &lds[(S_) * 8192 + (wid + 4) * 512]);        \
    GLD16(wl + bxs0 + (T_) * BK, &lds[(S_) * 8192 + 4096 + wid * 512]);       \
    GLD16(wl + bxs1 + (T_) * BK, &lds[(S_) * 8192 + 4096 + (wid + 4) * 512]); \
  }

#define COMPUTE(S_)                                                           \
  {                                                                           \
    bf16x8 af[4], bf[4];                                                      \
    _Pragma("unroll") for (int mi = 0; mi < 4; ++mi)                          \
        af[mi] = *(const bf16x8*)&lds[(S_) * 8192 + aoff + mi * 512];         \
    _Pragma("unroll") for (int ni = 0; ni < 4; ++ni)                          \
        bf[ni] = *(const bf16x8*)&lds[(S_) * 8192 + boff + ni * 512];         \
    asm volatile("s_waitcnt lgkmcnt(0)" ::: "memory");                        \
    __builtin_amdgcn_sched_barrier(0);                                        \
    __builtin_amdgcn_s_barrier(); /* all waves' reads of this slot done */    \
    __builtin_amdgcn_s_setprio(1);                                            \
    _Pragma("unroll") for (int mi = 0; mi < 4; ++mi)                          \
      _Pragma("unroll") for (int ni = 0; ni < 4; ++ni)                        \
          acc[mi][ni] = __builtin_amdgcn_mfma_f32_16x16x32_bf16(              \
              bf[ni], af[mi], acc[mi][ni], 0, 0, 0);                          \
    __builtin_amdgcn_s_setprio(0);                                            \
  }

  // BODY: stage(t+2), certify stage(t) landed, barrier, read+compute t
#define BODY(T_, S_, SN_)                                                     \
  {                                                                           \
    STAGE((T_) + 2, SN_);                                                     \
    asm volatile("s_waitcnt vmcnt(8)" ::: "memory");                          \
    __builtin_amdgcn_s_barrier();                                             \
    COMPUTE(S_);                                                              \
  }

  // prologue: slots 0,1 in flight
  STAGE(0, 0);
  STAGE(1, 1);

  // t = 0..20 (7 x 3, slots cycle 0,1,2)
#pragma unroll 1
  for (int tt = 0; tt < 7; ++tt) {
    const int t3 = tt * 3;
    BODY(t3 + 0, 0, 2);
    BODY(t3 + 1, 1, 0);
    BODY(t3 + 2, 2, 1);
  }
  // t = 21 (slot 0, stages tile 23 -> slot 2)
  BODY(21, 0, 2);
  // t = 22 (slot 1, no stage): outstanding = stage(23) only
  asm volatile("s_waitcnt vmcnt(4)" ::: "memory");
  __builtin_amdgcn_s_barrier();
  COMPUTE(1);
  // t = 23 (slot 2, no stage)
  asm volatile("s_waitcnt vmcnt(0)" ::: "memory");
  __builtin_amdgcn_s_barrier();
  COMPUTE(2);

  asm volatile("" ::: "memory");  // keep epilogue loads out of the loop

  float tau = ls[0];
  tau = fminf(fmaxf(tau, 0.01f), 2.5f);

  // swapped-operand C/D: m = l15 (col field), n = lq*4 + j (row field)
#pragma unroll
  for (int mi = 0; mi < 4; ++mi) {
    const int mg = a_row0 + wr * 64 + mi * 16 + l15;
    const float txm = tx[mg];
    float* orow = out + (size_t)mg * V;
#pragma unroll
    for (int ni = 0; ni < 4; ++ni) {
      const int nb = b_row0 + wc * 64 + ni * 16 + lq * 4;
      const f32x4 cw4 = *(const f32x4*)&cw[nb];
      f32x4 v;
#pragma unroll
      for (int j = 0; j < 4; ++j)
        v[j] = (acc[mi][ni][j] - txm * cw4[j]) * tau;
      if (nb + 3 < V) {
        __builtin_memcpy(&orow[nb], &v, 16);
      } else {
#pragma unroll
        for (int j = 0; j < 4; ++j)
          if (nb + j < V) orow[nb + j] = v[j];
      }
    }
  }
#undef STAGE
#undef COMPUTE
#undef BODY
}

extern "C" void kernel_launch(void* const* d_in, const int* in_sizes, int n_in,
                              void* d_out, int out_size, void* d_ws, size_t ws_size,
                              hipStream_t stream) {
  const float* h = (const float*)d_in[0];
  const float* w = (const float*)d_in[1];
  const float* ls = (const float*)d_in[2];
  float* out = (float*)d_out;

  const int M = in_sizes[0] / (KDIM + 1);        // 1024
  const int V = in_sizes[1] / KDIM;              // 50257
  const int Vpad = (V + BN - 1) & ~(BN - 1);     // 50304

  // workspace: wl bf16 [Vpad*768] | xl bf16 [M*768] | cw f32 [Vpad] | tx f32 [M]
  char* ws = (char*)d_ws;
  ushort_t* wl = (ushort_t*)ws;
  ushort_t* xl = (ushort_t*)(ws + (size_t)Vpad * KDIM * 2);
  float* cw = (float*)(ws + (size_t)Vpad * KDIM * 2 + (size_t)M * KDIM * 2);
  float* tx = cw + Vpad;

  prep_x_kernel<<<dim3(M), dim3(256), 0, stream>>>(h, xl, tx);
  prep_w_kernel<<<dim3(Vpad), dim3(256), 0, stream>>>(w, wl, cw, V);

  const int Mtiles = M / BM;                     // 8
  const int nwg = Mtiles * (Vpad / BN);          // 3144 (divisible by 8)
  gemm_kernel<<<dim3(nwg), dim3(256), 0, stream>>>(
      xl, wl, tx, cw, ls, out, V, Mtiles, nwg / 8);
}